// Round 4
// baseline (47.897 us; speedup 1.0000x reference)
//
#include <hip/hip_runtime.h>

typedef _Float16 half8 __attribute__((ext_vector_type(8)));
typedef float    f32x4 __attribute__((ext_vector_type(4)));

#define NLEN   8388608
#define KTAPS  257
#define MPAD   256
#define OUTLEN (NLEN + MPAD)        /* 8388864 = 256*32769 */
#define TPB    512
#define BT     8192                 /* complex outputs per block */
#define NBLK   ((OUTLEN + BT - 1) / BT)   /* 1025 */
#define NCH    9                    /* K chunks of 32 -> GEMM-K = 288 */
#define XELEM  (BT + 288)           /* staged elems per component: 8480 */
#define XSLOT  (XELEM / 8)          /* 1060 16B slots */
#define XPAD   1068                 /* + swizzle margin */
#define NXCD   8

__device__ __forceinline__ int swz(int t) { return t ^ ((t >> 3) & 7); }

__global__ __launch_bounds__(TPB, 6) void cconv_mfma(
    const float* __restrict__ xr, const float* __restrict__ xi,
    const float* __restrict__ wr, const float* __restrict__ wi,
    float* __restrict__ out)
{
    __shared__ half8 lx[2][XPAD];        /* staged signal, fp16, swizzled slots */
    __shared__ half8 af[2][NCH][64];     /* weight A-fragments, MFMA layout    */

    const int tid   = threadIdx.x;
    const int wv    = tid >> 6;
    const int lane  = tid & 63;
    const int n15   = lane & 15;
    const int lg    = lane >> 4;

    /* ---- bijective XCD-aware block swizzle (nwg=1025, q=128, r=1) ---- */
    const int bidr = blockIdx.x;
    const int q    = NBLK / NXCD, r = NBLK % NXCD;
    const int xcd  = bidr % NXCD, idx = bidr / NXCD;
    const int bid  = (xcd < r ? xcd * (q + 1) : r * (q + 1) + (xcd - r) * q) + idx;

    const int t0    = bid * BT;
    const int xbase = t0 - MPAD;         /* global elem of lx slot 0 */

    /* ---- build weight fragments: A[m][j] = w[j-m], lane l: m=l&15, j=32c+8*(l>>4)+e ---- */
    for (int i = tid; i < 2 * NCH * 64; i += TPB) {
        const int comp = i / (NCH * 64);
        const int rem  = i % (NCH * 64);
        const int c    = rem >> 6;
        const int l    = rem & 63;
        const int row  = l & 15;
        const int jb   = 32 * c + 8 * (l >> 4);
        const float* wp = comp ? wi : wr;
        half8 v;
        #pragma unroll
        for (int e = 0; e < 8; ++e) {
            const int k = jb + e - row;
            const float f = (k >= 0 && k < KTAPS) ? wp[k] : 0.0f;
            v[e] = (_Float16)f;
        }
        af[comp][c][l] = v;
    }

    /* ---- stage x: fp32 -> fp16, 8 elems/thread/iter, swizzled slot write ---- */
    const bool interior = (xbase >= 0) && (xbase + 8 * XSLOT <= NLEN);
    if (interior) {
        for (int T = tid; T < XSLOT; T += TPB) {
            const int g = xbase + 8 * T;
            const f32x4 a0 = *(const f32x4*)(xr + g);
            const f32x4 a1 = *(const f32x4*)(xr + g + 4);
            const f32x4 b0 = *(const f32x4*)(xi + g);
            const f32x4 b1 = *(const f32x4*)(xi + g + 4);
            half8 vrr, vii;
            #pragma unroll
            for (int e = 0; e < 4; ++e) {
                vrr[e]     = (_Float16)a0[e];
                vrr[e + 4] = (_Float16)a1[e];
                vii[e]     = (_Float16)b0[e];
                vii[e + 4] = (_Float16)b1[e];
            }
            const int Ts = swz(T);
            lx[0][Ts] = vrr;
            lx[1][Ts] = vii;
        }
    } else {
        for (int T = tid; T < XSLOT; T += TPB) {
            const int g = xbase + 8 * T;
            half8 vrr, vii;
            #pragma unroll
            for (int e = 0; e < 8; ++e) {
                const int ge = g + e;
                const bool ok = (ge >= 0) && (ge < NLEN);
                vrr[e] = (_Float16)(ok ? xr[ge] : 0.0f);
                vii[e] = (_Float16)(ok ? xi[ge] : 0.0f);
            }
            const int Ts = swz(T);
            lx[0][Ts] = vrr;
            lx[1][Ts] = vii;
        }
    }
    __syncthreads();

    /* ---- main loop: 4 tiles/wave, 9 K-chunks, 4 MFMAs each ---- */
    f32x4 accr[4], acci[4];
    #pragma unroll
    for (int t = 0; t < 4; ++t) {
        accr[t] = (f32x4)0.0f;
        acci[t] = (f32x4)0.0f;
    }

    const int sT0 = 128 * wv + 2 * n15 + lg;   /* base 16B slot for this lane */

    #pragma unroll
    for (int c = 0; c < NCH; ++c) {
        const half8 awr = af[0][c][lane];
        const half8 awi = af[1][c][lane];
        #pragma unroll
        for (int t = 0; t < 4; ++t) {
            const int T  = sT0 + 32 * t + 4 * c;
            const int Ts = swz(T);
            const half8 br  = lx[0][Ts];
            const half8 bi  = lx[1][Ts];
            const half8 bin = -bi;           /* exact fp16 sign flip */
            accr[t] = __builtin_amdgcn_mfma_f32_16x16x32_f16(awr, br,  accr[t], 0, 0, 0);
            accr[t] = __builtin_amdgcn_mfma_f32_16x16x32_f16(awi, bin, accr[t], 0, 0, 0);
            acci[t] = __builtin_amdgcn_mfma_f32_16x16x32_f16(awr, bi,  acci[t], 0, 0, 0);
            acci[t] = __builtin_amdgcn_mfma_f32_16x16x32_f16(awi, br,  acci[t], 0, 0, 0);
        }
    }

    /* ---- epilogue: lane l holds D[4*lg + r][n15] -> 4 consecutive outputs ---- */
    const int obase = t0 + 1024 * wv + 16 * n15 + 4 * lg;
    #pragma unroll
    for (int t = 0; t < 4; ++t) {
        const int tbase = t0 + 1024 * wv + 256 * t;   /* tile base, mult of 256 */
        if (tbase < OUTLEN) {                          /* tiles fully in or out  */
            const int pos = obase + 256 * t;
            __builtin_nontemporal_store(accr[t], (f32x4*)(out + pos));
            __builtin_nontemporal_store(acci[t], (f32x4*)(out + OUTLEN + pos));
        }
    }
}

extern "C" void kernel_launch(void* const* d_in, const int* in_sizes, int n_in,
                              void* d_out, int out_size, void* d_ws, size_t ws_size,
                              hipStream_t stream) {
    const float* xr = (const float*)d_in[0];
    const float* xi = (const float*)d_in[1];
    const float* wr = (const float*)d_in[2];
    const float* wi = (const float*)d_in[3];
    float* o = (float*)d_out;
    cconv_mfma<<<NBLK, TPB, 0, stream>>>(xr, xi, wr, wi, o);
}